// Round 9
// baseline (265.952 us; speedup 1.0000x reference)
//
#include <hip/hip_runtime.h>
#include <hip/hip_bf16.h>
#include <stdint.h>

// Problem constants (fixed by reference setup_inputs)
#define T_TOKENS 32768     // 32*1024
#define D_IN     768
#define D_OUT    256
#define N_EXP    8
#define S_TOT    (T_TOKENS*2)   // 65536 routed slots
#define S_PAD    66560          // 65536 + 8*128 worst-case per-expert 128-padding
#define NKB      24             // K-blocks of 32 in d_in
#define NT2      12             // double K-steps (BK=64)

typedef __attribute__((ext_vector_type(8))) short bf16x8;
typedef __attribute__((ext_vector_type(4))) float f32x4;

__device__ __forceinline__ unsigned short f2bf(float f) {
    unsigned u = __float_as_uint(f);
    return (unsigned short)((u + 0x7FFFu + ((u >> 16) & 1u)) >> 16);  // RNE
}
__device__ __forceinline__ unsigned pack_bf2(float a, float b) {
    return (unsigned)f2bf(a) | ((unsigned)f2bf(b) << 16);
}

// async global->LDS, 16B per lane. LDS dest must be wave-uniform base + lane*16.
__device__ __forceinline__ void async16(void* lds, const void* g) {
    __builtin_amdgcn_global_load_lds(
        (const __attribute__((address_space(1))) unsigned int*)g,
        (__attribute__((address_space(3))) unsigned int*)lds, 16, 0, 0);
}

// ---- W fp32 [e][k][n] -> bf16 k-blocked [e][kb][n][32kk]; zeroes counts+cursors ----
// Each (e,kb) tile is a contiguous 16 KB slab -> GEMM B reads are fully coalesced.
__global__ __launch_bounds__(256) void convw_kernel(
        const float* __restrict__ W, unsigned short* __restrict__ WTb,
        int* __restrict__ zero16) {
    if (blockIdx.x == 0 && threadIdx.x < 16) zero16[threadIdx.x] = 0;  // counts+cursors
    int eb_ = blockIdx.x;                            // e*NKB + kb, 0..191
    int n = threadIdx.x;
    const float* src = W + ((size_t)(eb_ / NKB) * D_IN + (eb_ % NKB) * 32) * 256 + n;
    unsigned pk[16];
    #pragma unroll
    for (int j = 0; j < 16; j++)                     // reads coalesced (n fastest)
        pk[j] = pack_bf2(src[(2*j) * 256], src[(2*j+1) * 256]);
    unsigned* dst = (unsigned*)(WTb + ((size_t)eb_ * 256 + n) * 32);  // 64 B/thread contig
    #pragma unroll
    for (int j = 0; j < 16; j++) dst[j] = pk[j];
}

// ---- gate v4 (R9): lane = token, gW via SCALAR loads (SGPR operands) ----
// R8 counters: gate 60.6 us, VALUBusy 18%, HBM 21%, conflicts 0 -> no pipe
// saturated; cost = sum of LDS-issue (~15 us, gW operand reads) + VMEM (~18) +
// VALU (~11), poorly overlapped. Fix: gW operands are wave-uniform -> feed them
// through s_load/SGPR (free on VALU+LDS pipes). Wave = 64 tokens (lane = token);
// 4 waves split k into quarters (192 k). Per 32-k chunk: reg-stage x (8 coalesced
// float4/lane), emit xbf from regs, ds_write into a PRIVATE per-wave 64x33 tile
// (no block barrier in the loop), compute xv from column reads (stride 33:
// conflict-free), FMA with uniform gW loads. One __syncthreads total for the
// cross-wave k-quarter reduce (fixed order). Histogram via ballots.
__global__ __launch_bounds__(256) void gate_v4_kernel(
        const float* __restrict__ x, const float* __restrict__ gW,
        const float* __restrict__ gb, unsigned short* __restrict__ xbf,
        float* __restrict__ topk_w, int* __restrict__ topk_e,
        int* __restrict__ counts) {
    __shared__ float lds[4][2112];                   // 33.8 KB: per-wave 64x33 tiles
    int tid = threadIdx.x;
    int w = tid >> 6, l = tid & 63;
    int t0 = blockIdx.x * 64;
    int kb = w * 192;                                // this wave's k-quarter
    int ti = l >> 3, kloc = (l & 7) * 4;             // stage map: 8 tokens x 32 k
    const float*    xsrc = x   + (size_t)(t0 + ti) * D_IN + kb + kloc;
    unsigned short* xdst = xbf + (size_t)(t0 + ti) * D_IN + kb + kloc;
    float* myt = &lds[w][0];

    float4 rv[8];
    #pragma unroll
    for (int i = 0; i < 8; ++i)                      // prologue: chunk 0 -> regs
        rv[i] = *(const float4*)(xsrc + (size_t)i * 8 * D_IN);
    float acc[8] = {0,0,0,0,0,0,0,0};

    #pragma unroll 1
    for (int c = 0; c < 6; ++c) {
        #pragma unroll
        for (int i = 0; i < 8; ++i) {                // regs -> LDS tile + xbf emit
            float4 v = rv[i];
            *(float4*)&myt[(ti + 8 * i) * 33 + kloc] = v;
            uint2 p; p.x = pack_bf2(v.x, v.y); p.y = pack_bf2(v.z, v.w);
            *(uint2*)(xdst + (size_t)i * 8 * D_IN + c * 32) = p;
        }
        if (c < 5) {                                 // prefetch next chunk (hides HBM)
            #pragma unroll
            for (int i = 0; i < 8; ++i)
                rv[i] = *(const float4*)(xsrc + (size_t)i * 8 * D_IN + (c + 1) * 32);
        }
        const float* gWc = gW + (size_t)(kb + c * 32) * 8;   // wave-uniform
        #pragma unroll
        for (int k = 0; k < 32; ++k) {
            float xv = myt[l * 33 + k];              // bank (l+k)%32: conflict-free
            const float* gr = gWc + k * 8;           // uniform -> s_load_dwordx8
            #pragma unroll
            for (int e = 0; e < 8; ++e) acc[e] = fmaf(xv, gr[e], acc[e]);
        }
    }
    // cross-wave k-quarter reduce (overlay on own tile region; fixed order)
    #pragma unroll
    for (int e = 0; e < 8; ++e) myt[l * 9 + e] = acc[e];     // 9-pad: banks distinct
    __syncthreads();
    if (w == 0) {
        int t = t0 + l;                              // one token per lane, all parallel
        float s8[8];
        #pragma unroll
        for (int e = 0; e < 8; ++e)
            s8[e] = ((lds[0][l*9+e] + lds[1][l*9+e])
                   + (lds[2][l*9+e] + lds[3][l*9+e])) + gb[e];
        float mx = -1e30f;
        #pragma unroll
        for (int e = 0; e < 8; ++e) mx = fmaxf(mx, s8[e]);
        float pw[8], s = 0.f;
        #pragma unroll
        for (int e = 0; e < 8; ++e) { pw[e] = expf(s8[e] - mx); s += pw[e]; }
        float inv = 1.0f / s;
        int e0 = 0; float b0 = -1.f;
        #pragma unroll
        for (int e = 0; e < 8; ++e) if (pw[e] > b0) { b0 = pw[e]; e0 = e; }
        int e1 = 0; float b1 = -1.f;
        #pragma unroll
        for (int e = 0; e < 8; ++e) if (e != e0 && pw[e] > b1) { b1 = pw[e]; e1 = e; }
        topk_w[t*2]   = b0 * inv;
        topk_w[t*2+1] = b1 * inv;
        topk_e[t*2]   = e0;
        topk_e[t*2+1] = e1;
        int my = 0;                                  // wave histogram via ballots
        #pragma unroll
        for (int e = 0; e < 8; ++e) {
            unsigned long long m0 = __ballot(e0 == e);
            unsigned long long m1 = __ballot(e1 == e);
            if (l == e) my = __popcll(m0) + __popcll(m1);
        }
        if (l < 8) atomicAdd(&counts[l], my);
    }
}

// ---- scatter (token,w) into expert buckets + inverse map; 128-aligned regions ----
// Block 0 additionally zeroes slot_w over the interior pad gaps (<=127 per expert).
__global__ void scatter_kernel(const int* __restrict__ topk_e, const float* __restrict__ topk_w,
                               const int* __restrict__ counts, int* __restrict__ cursors,
                               int* __restrict__ slot_token, float* __restrict__ slot_w,
                               int* __restrict__ inv_slot) {
    int offs[9]; offs[0] = 0;
    #pragma unroll
    for (int e = 0; e < 8; e++) offs[e+1] = offs[e] + ((counts[e] + 127) & ~127);
    if (blockIdx.x == 0) {                           // zero pad-gap weights
        #pragma unroll
        for (int e = 0; e < 8; e++) {
            int start = offs[e] + counts[e];
            for (int i = start + threadIdx.x; i < offs[e+1]; i += 256) slot_w[i] = 0.f;
        }
    }
    __shared__ int hcnt[8], hbase[8];
    if (threadIdx.x < 8) hcnt[threadIdx.x] = 0;
    __syncthreads();
    int idx[4], ee[4], lr[4];
    int base = blockIdx.x * 256 * 4 + threadIdx.x;
    #pragma unroll
    for (int j = 0; j < 4; j++) {
        idx[j] = base + j * 256;
        ee[j]  = topk_e[idx[j]];
        lr[j]  = atomicAdd(&hcnt[ee[j]], 1);
    }
    __syncthreads();
    if (threadIdx.x < 8) hbase[threadIdx.x] = atomicAdd(&cursors[threadIdx.x], hcnt[threadIdx.x]);
    __syncthreads();
    #pragma unroll
    for (int j = 0; j < 4; j++) {
        int slot = offs[ee[j]] + hbase[ee[j]] + lr[j];
        slot_token[slot] = idx[j] >> 1;
        slot_w[slot]     = topk_w[idx[j]];
        inv_slot[idx[j]] = slot;
    }
}

// ---- routed GEMM (unchanged from R8): BK=64, 128x256 tile, 512 thr / 8 waves
// 1Mx8N, B global->VGPR (bEv loop-carried, bOdd intra-step), A via 3-stage
// gload_lds (2 async16/thread/stage), counted vmcnt, 48 KB LDS.
template<bool ROUTED>
__global__ __launch_bounds__(512, 4) void moe_gemm_kernel(
        const unsigned short* __restrict__ xbf, const unsigned short* __restrict__ WTb,
        const float* __restrict__ eb, const int* __restrict__ counts,
        const int* __restrict__ slot_token, const float* __restrict__ slot_w,
        float* __restrict__ dst) {
    __shared__ unsigned short A_lds[3][2][128 * 32];  // 3 x 16 KB = 48 KB

    // bijective XCD-chunked swizzle: 520 = 8 * 65; consecutive lbid share B panel
    int lbid = (blockIdx.x & 7) * ((int)gridDim.x >> 3) + (blockIdx.x >> 3);

    int offs[9]; offs[0] = 0;
    #pragma unroll
    for (int e = 0; e < 8; e++) offs[e+1] = offs[e] + ((counts[e] + 127) & ~127);
    int row0 = lbid * 128;
    if (row0 >= offs[8]) return;                     // uniform exit (pad tiles)
    int expert = 0;
    #pragma unroll
    for (int e = 0; e < 8; e++) if (row0 >= offs[e]) expert = e;

    int tid  = threadIdx.x;
    int wave = tid >> 6, lane = tid & 63;
    int lrow = lane & 15, lquad = lane >> 4;
    int wn = wave;                                   // 1 (M) x 8 (N) wave grid

    // A: per 32-k block, 512 16B-chunks (128 rows x 4) = 1 chunk/thread
    int ar = tid >> 2, ap = tid & 3;
    int alc = (ap - (ar >> 1)) & 3;                  // logical chunk at this phys slot
    int tok = slot_token[row0 + ar];
    tok = (tok < 0 || tok >= T_TOKENS) ? 0 : tok;    // pad slots hold garbage: clamp
    const unsigned short* asrc = xbf + (size_t)tok * D_IN + alc * 8;

    // B direct-load base: wave covers contiguous 1 KB per q (16 rows x 4 lquad chunks)
    const unsigned short* bptr = WTb + (size_t)expert * NKB * 8192
                                     + (wn * 32 + lrow) * 32 + lquad * 8;

    // A frag LDS offsets (shorts) within one 8 KB k-block; constant across K
    int a_off[8];
    #pragma unroll
    for (int m = 0; m < 8; m++) {
        int r = m * 16 + lrow;
        a_off[m] = r * 32 + ((lquad + (r >> 1)) & 3) * 8;
    }

    f32x4 acc[8][2];
    #pragma unroll
    for (int m = 0; m < 8; m++)
        #pragma unroll
        for (int q = 0; q < 2; q++) acc[m][q] = (f32x4){0,0,0,0};

    auto bload = [&](int kb, bf16x8 (&b)[2]) {
        const unsigned short* bp = bptr + (size_t)kb * 8192;
        #pragma unroll
        for (int q = 0; q < 2; q++) b[q] = *(const bf16x8*)(bp + q * 512);
    };
    auto stageA = [&](int st, int t2) {              // 2 async16: k-blocks 2t2, 2t2+1
        async16(&A_lds[st][0][tid * 8], asrc + (2 * t2) * 32);
        async16(&A_lds[st][1][tid * 8], asrc + (2 * t2 + 1) * 32);
    };
    auto half = [&](const unsigned short* base, bf16x8 (&b)[2]) {
        #pragma unroll
        for (int g = 0; g < 2; ++g) {                // a-frags in 2 groups of 4
            bf16x8 a[4];
            #pragma unroll
            for (int m = 0; m < 4; ++m) a[m] = *(const bf16x8*)&base[a_off[g*4+m]];
            __builtin_amdgcn_s_setprio(1);
            #pragma unroll
            for (int q = 0; q < 2; ++q)
                #pragma unroll
                for (int m = 0; m < 4; ++m)
                    acc[g*4+m][q] = __builtin_amdgcn_mfma_f32_16x16x32_bf16(
                        a[m], b[q], acc[g*4+m][q], 0, 0, 0);
            __builtin_amdgcn_s_setprio(0);
        }
    };

    // prologue: A stages oldest in vmcnt FIFO, then B(0)
    stageA(0, 0);
    stageA(1, 1);
    __builtin_amdgcn_sched_barrier(0);               // pin A stages before bload
    bf16x8 bEv[2];
    bload(0, bEv);

    for (int t = 0; t < NT2; ++t) {
        if (t == 0 || t == NT2 - 1) asm volatile("s_waitcnt vmcnt(4)" ::: "memory");
        else                        asm volatile("s_waitcnt vmcnt(6)" ::: "memory");
        asm volatile("s_barrier" ::: "memory");      // raw: no compiler vmcnt(0) drain
        bf16x8 bOdd[2];
        bload(2 * t + 1, bOdd);                      // 2 VMEM
        if (t + 2 < NT2) stageA((t + 2) % 3, t + 2); // 2 VMEM (overwrites stage t-1)
        half(&A_lds[t % 3][0][0], bEv);              // k-block 2t
        bf16x8 bEvN[2];
        if (t + 1 < NT2) bload(2 * t + 2, bEvN);     // 2 VMEM (next even block)
        half(&A_lds[t % 3][1][0], bOdd);             // k-block 2t+1
        if (t + 1 < NT2) { bEv[0] = bEvN[0]; bEv[1] = bEvN[1]; }
    }

    // epilogue: D mapping col=lane&15, row=quad*4+reg
    float bias_q[2];
    #pragma unroll
    for (int q = 0; q < 2; q++)
        bias_q[q] = eb[expert * D_OUT + wn * 32 + q * 16 + lrow];
    #pragma unroll
    for (int m = 0; m < 8; m++) {
        #pragma unroll
        for (int r = 0; r < 4; r++) {
            int slot = row0 + m * 16 + lquad * 4 + r;
            if constexpr (ROUTED) {
                float* drow = dst + (size_t)slot * D_OUT + wn * 32;
                #pragma unroll
                for (int q = 0; q < 2; q++)
                    drow[q * 16 + lrow] = acc[m][q][r] + bias_q[q];
            } else {
                int tk = slot_token[slot];
                float wgt = slot_w[slot];            // pads have wgt=0 (memset path)
                if (wgt != 0.f) {
                    #pragma unroll
                    for (int q = 0; q < 2; q++)
                        atomicAdd(dst + (size_t)tk * D_OUT + wn * 32 + q * 16 + lrow,
                                  wgt * (acc[m][q][r] + bias_q[q]));
                }
            }
        }
    }
}

// ---------------- combine: out[t] = w0*routed[s0] + w1*routed[s1] ----------------
__global__ void combine_kernel(const float* __restrict__ routed, const int* __restrict__ inv_slot,
                               const float* __restrict__ topk_w, float* __restrict__ out) {
    int flat = blockIdx.x * 256 + threadIdx.x;       // float4 index
    int t = flat >> 6, c = (flat & 63) * 4;
    int   s0 = inv_slot[t*2], s1 = inv_slot[t*2+1];
    float w0 = topk_w[t*2],   w1 = topk_w[t*2+1];
    float4 r0 = *(const float4*)(routed + (size_t)s0 * D_OUT + c);
    float4 r1 = *(const float4*)(routed + (size_t)s1 * D_OUT + c);
    float4 o;
    o.x = w0*r0.x + w1*r1.x; o.y = w0*r0.y + w1*r1.y;
    o.z = w0*r0.z + w1*r1.z; o.w = w0*r0.w + w1*r1.w;
    *(float4*)(out + (size_t)t * D_OUT + c) = o;
}

extern "C" void kernel_launch(void* const* d_in, const int* in_sizes, int n_in,
                              void* d_out, int out_size, void* d_ws, size_t ws_size,
                              hipStream_t stream) {
    const float* x  = (const float*)d_in[0];
    const float* gW = (const float*)d_in[1];
    const float* gb = (const float*)d_in[2];
    const float* eW = (const float*)d_in[3];
    const float* eb = (const float*)d_in[4];
    float* out = (float*)d_out;
    char* ws = (char*)d_ws;

    // ws layout
    float* topk_w      = (float*)(ws + 0);                 // 256 KB
    int*   topk_e      = (int*)  (ws + 262144);            // 256 KB
    int*   counts      = (int*)  (ws + 524288);            // 8 ints
    int*   cursors     = (int*)  (ws + 524320);            // 8 ints  (contiguous w/ counts)
    int*   slot_token  = (int*)  (ws + 524416);            // 266240 B (S_PAD)
    float* slot_w      = (float*)(ws + 790656);            // 266240 B (S_PAD)
    int*   inv_slot    = (int*)  (ws + 1056896);           // 262144 B (S_TOT)
    unsigned short* WTb= (unsigned short*)(ws + 7610496);  // 3 MB bf16 W k-blocked
    unsigned short* xbf= (unsigned short*)(ws + 10756224); // 48 MB bf16 x
    float* routed      = (float*)(ws + 61087872);          // 68 MB routed outputs
    const size_t NEED_ROUTED = 61087872 + (size_t)S_PAD * D_OUT * 4;  // ~129 MB
    bool use_routed = (ws_size >= NEED_ROUTED);

    convw_kernel   <<<N_EXP * NKB, 256, 0, stream>>>(eW, WTb, counts);
    gate_v4_kernel <<<T_TOKENS / 64, 256, 0, stream>>>(x, gW, gb, xbf,
                                                       topk_w, topk_e, counts);
    scatter_kernel <<<S_TOT / (256 * 4), 256, 0, stream>>>(topk_e, topk_w, counts, cursors,
                                                           slot_token, slot_w, inv_slot);
    if (use_routed) {
        moe_gemm_kernel<true><<<S_PAD / 128, 512, 0, stream>>>(xbf, WTb, eb, counts,
                                                               slot_token, slot_w, routed);
        combine_kernel<<<T_TOKENS * D_OUT / 4 / 256, 256, 0, stream>>>(routed, inv_slot,
                                                                       topk_w, out);
    } else {
        // fallback: pads must be (token=0, w=0) for the atomic path
        hipMemsetAsync(slot_token, 0, 532480, stream);
        hipMemsetAsync(out, 0, (size_t)out_size * sizeof(float), stream);
        moe_gemm_kernel<false><<<S_PAD / 128, 512, 0, stream>>>(xbf, WTb, eb, counts,
                                                                slot_token, slot_w, out);
    }
}

// Round 10
// 237.954 us; speedup vs baseline: 1.1177x; 1.1177x over previous
//
#include <hip/hip_runtime.h>
#include <hip/hip_bf16.h>
#include <stdint.h>

// Problem constants (fixed by reference setup_inputs)
#define T_TOKENS 32768     // 32*1024
#define D_IN     768
#define D_OUT    256
#define N_EXP    8
#define S_TOT    (T_TOKENS*2)   // 65536 routed slots
#define S_PAD    66560          // 65536 + 8*128 worst-case per-expert 128-padding
#define NKB      24             // K-blocks of 32 in d_in
#define NT2      12             // double K-steps (BK=64)

typedef __attribute__((ext_vector_type(8))) short bf16x8;
typedef __attribute__((ext_vector_type(4))) float f32x4;

__device__ __forceinline__ unsigned short f2bf(float f) {
    unsigned u = __float_as_uint(f);
    return (unsigned short)((u + 0x7FFFu + ((u >> 16) & 1u)) >> 16);  // RNE
}
__device__ __forceinline__ unsigned pack_bf2(float a, float b) {
    return (unsigned)f2bf(a) | ((unsigned)f2bf(b) << 16);
}

// async global->LDS, 16B per lane. LDS dest must be wave-uniform base + lane*16.
__device__ __forceinline__ void async16(void* lds, const void* g) {
    __builtin_amdgcn_global_load_lds(
        (const __attribute__((address_space(1))) unsigned int*)g,
        (__attribute__((address_space(3))) unsigned int*)lds, 16, 0, 0);
}

// ---- W fp32 [e][k][n] -> bf16 k-blocked [e][kb][n][32kk]; zeroes counts+cursors ----
// Each (e,kb) tile is a contiguous 16 KB slab -> GEMM B reads are fully coalesced.
__global__ __launch_bounds__(256) void convw_kernel(
        const float* __restrict__ W, unsigned short* __restrict__ WTb,
        int* __restrict__ zero16) {
    if (blockIdx.x == 0 && threadIdx.x < 16) zero16[threadIdx.x] = 0;  // counts+cursors
    int eb_ = blockIdx.x;                            // e*NKB + kb, 0..191
    int n = threadIdx.x;
    const float* src = W + ((size_t)(eb_ / NKB) * D_IN + (eb_ % NKB) * 32) * 256 + n;
    unsigned pk[16];
    #pragma unroll
    for (int j = 0; j < 16; j++)                     // reads coalesced (n fastest)
        pk[j] = pack_bf2(src[(2*j) * 256], src[(2*j+1) * 256]);
    unsigned* dst = (unsigned*)(WTb + ((size_t)eb_ * 256 + n) * 32);  // 64 B/thread contig
    #pragma unroll
    for (int j = 0; j < 16; j++) dst[j] = pk[j];
}

// ---- gate v5 (R10): v3 data path + max TLP/MLP ----
// Gate ledger: v1..v4 = 60/59/60.6/72.9 us across 4 structures; invariants were the
// streams, MLP<=4 loads in flight, and 16 waves/CU. v5 attacks latency-hiding only:
// 2048 blocks x 16 tokens (16 lanes/token); ALL 12 x-float4s loaded up front
// (12 independent VMEM in flight/thread); 256B contiguous per (wave,chunk);
// 24.6 KB LDS -> 6 blocks/CU -> 24 waves/CU (75%). gW in LDS, XOR-swizzled
// broadcast reads (16 distinct addrs/instr, 2-way alias = free). One barrier pair.
__global__ __launch_bounds__(256) void gate_v5_kernel(
        const float* __restrict__ x, const float* __restrict__ gW,
        const float* __restrict__ gb, unsigned short* __restrict__ xbf,
        float* __restrict__ topk_w, int* __restrict__ topk_e,
        int* __restrict__ counts) {
    __shared__ float4 gws4[1536];                    // 24 KB: swizzled gW [768][8]
    __shared__ int h8[8];
    int tid = threadIdx.x;
    if (tid < 8) h8[tid] = 0;                        // covered by the barrier below
    #pragma unroll
    for (int i = 0; i < 6; ++i) {                    // cooperative gW load, coalesced
        int f = tid + i * 256;                       // f4 index over [768][8]
        gws4[f ^ ((f >> 3) & 7)] = *(const float4*)(gW + f * 4);
    }
    int tt = tid >> 4, qq = tid & 15;                // token x k-sixteenth
    int q7 = qq & 7;
    int t  = blockIdx.x * 16 + tt;
    const float*    xrow  = x   + (size_t)t * D_IN + qq * 4;
    unsigned short* xbrow = xbf + (size_t)t * D_IN + qq * 4;
    float4 v[12];
    #pragma unroll
    for (int kk = 0; kk < 12; ++kk)                  // ALL loads issued up front
        v[kk] = *(const float4*)(xrow + kk * 64);    // 256B/ (wave,kk), coalesced
    __syncthreads();                                 // gws4 + h8 visible
    float acc[8] = {0,0,0,0,0,0,0,0};
    #pragma unroll
    for (int kk = 0; kk < 12; ++kk) {
        float4 vv = v[kk];
        uint2 p; p.x = pack_bf2(vv.x, vv.y); p.y = pack_bf2(vv.z, vv.w);
        *(uint2*)(xbrow + kk * 64) = p;              // fused bf16 emit
        float va[4] = {vv.x, vv.y, vv.z, vv.w};
        #pragma unroll
        for (int j = 0; j < 4; ++j) {                // k = 64kk + 4qq + j
            int i0 = 128 * kk + 8 * qq + 2 * j;      // orig f4 idx of gW[k][0:4]
            float4 g0 = gws4[i0 ^ q7];               // (i0>>3)&7 == qq&7
            float4 g1 = gws4[(i0 + 1) ^ q7];
            float xv = va[j];
            acc[0] += xv * g0.x; acc[1] += xv * g0.y;
            acc[2] += xv * g0.z; acc[3] += xv * g0.w;
            acc[4] += xv * g1.x; acc[5] += xv * g1.y;
            acc[6] += xv * g1.z; acc[7] += xv * g1.w;
        }
    }
    #pragma unroll
    for (int e = 0; e < 8; ++e) {                    // fixed-order 16-lane reduce
        acc[e] += __shfl_xor(acc[e], 1);
        acc[e] += __shfl_xor(acc[e], 2);
        acc[e] += __shfl_xor(acc[e], 4);
        acc[e] += __shfl_xor(acc[e], 8);
    }
    if (qq == 0) {
        float mx = -1e30f;
        #pragma unroll
        for (int e = 0; e < 8; ++e) { acc[e] += gb[e]; mx = fmaxf(mx, acc[e]); }
        float w[8], s = 0.f;
        #pragma unroll
        for (int e = 0; e < 8; ++e) { w[e] = expf(acc[e] - mx); s += w[e]; }
        float inv = 1.0f / s;
        int e0 = 0; float b0 = -1.f;
        #pragma unroll
        for (int e = 0; e < 8; ++e) if (w[e] > b0) { b0 = w[e]; e0 = e; }
        int e1 = 0; float b1 = -1.f;
        #pragma unroll
        for (int e = 0; e < 8; ++e) if (e != e0 && w[e] > b1) { b1 = w[e]; e1 = e; }
        topk_w[t*2]   = b0 * inv;
        topk_w[t*2+1] = b1 * inv;
        topk_e[t*2]   = e0;
        topk_e[t*2+1] = e1;
        atomicAdd(&h8[e0], 1); atomicAdd(&h8[e1], 1);
    }
    __syncthreads();
    if (tid < 8) atomicAdd(&counts[tid], h8[tid]);
}

// ---- scatter (token,w) into expert buckets + inverse map; 128-aligned regions ----
// Block 0 additionally zeroes slot_w over the interior pad gaps (<=127 per expert).
__global__ void scatter_kernel(const int* __restrict__ topk_e, const float* __restrict__ topk_w,
                               const int* __restrict__ counts, int* __restrict__ cursors,
                               int* __restrict__ slot_token, float* __restrict__ slot_w,
                               int* __restrict__ inv_slot) {
    int offs[9]; offs[0] = 0;
    #pragma unroll
    for (int e = 0; e < 8; e++) offs[e+1] = offs[e] + ((counts[e] + 127) & ~127);
    if (blockIdx.x == 0) {                           // zero pad-gap weights
        #pragma unroll
        for (int e = 0; e < 8; e++) {
            int start = offs[e] + counts[e];
            for (int i = start + threadIdx.x; i < offs[e+1]; i += 256) slot_w[i] = 0.f;
        }
    }
    __shared__ int hcnt[8], hbase[8];
    if (threadIdx.x < 8) hcnt[threadIdx.x] = 0;
    __syncthreads();
    int idx[4], ee[4], lr[4];
    int base = blockIdx.x * 256 * 4 + threadIdx.x;
    #pragma unroll
    for (int j = 0; j < 4; j++) {
        idx[j] = base + j * 256;
        ee[j]  = topk_e[idx[j]];
        lr[j]  = atomicAdd(&hcnt[ee[j]], 1);
    }
    __syncthreads();
    if (threadIdx.x < 8) hbase[threadIdx.x] = atomicAdd(&cursors[threadIdx.x], hcnt[threadIdx.x]);
    __syncthreads();
    #pragma unroll
    for (int j = 0; j < 4; j++) {
        int slot = offs[ee[j]] + hbase[ee[j]] + lr[j];
        slot_token[slot] = idx[j] >> 1;
        slot_w[slot]     = topk_w[idx[j]];
        inv_slot[idx[j]] = slot;
    }
}

// ---- routed GEMM (unchanged from R8): BK=64, 128x256 tile, 512 thr / 8 waves
// 1Mx8N, B global->VGPR (bEv loop-carried, bOdd intra-step), A via 3-stage
// gload_lds (2 async16/thread/stage), counted vmcnt, 48 KB LDS.
template<bool ROUTED>
__global__ __launch_bounds__(512, 4) void moe_gemm_kernel(
        const unsigned short* __restrict__ xbf, const unsigned short* __restrict__ WTb,
        const float* __restrict__ eb, const int* __restrict__ counts,
        const int* __restrict__ slot_token, const float* __restrict__ slot_w,
        float* __restrict__ dst) {
    __shared__ unsigned short A_lds[3][2][128 * 32];  // 3 x 16 KB = 48 KB

    // bijective XCD-chunked swizzle: 520 = 8 * 65; consecutive lbid share B panel
    int lbid = (blockIdx.x & 7) * ((int)gridDim.x >> 3) + (blockIdx.x >> 3);

    int offs[9]; offs[0] = 0;
    #pragma unroll
    for (int e = 0; e < 8; e++) offs[e+1] = offs[e] + ((counts[e] + 127) & ~127);
    int row0 = lbid * 128;
    if (row0 >= offs[8]) return;                     // uniform exit (pad tiles)
    int expert = 0;
    #pragma unroll
    for (int e = 0; e < 8; e++) if (row0 >= offs[e]) expert = e;

    int tid  = threadIdx.x;
    int wave = tid >> 6, lane = tid & 63;
    int lrow = lane & 15, lquad = lane >> 4;
    int wn = wave;                                   // 1 (M) x 8 (N) wave grid

    // A: per 32-k block, 512 16B-chunks (128 rows x 4) = 1 chunk/thread
    int ar = tid >> 2, ap = tid & 3;
    int alc = (ap - (ar >> 1)) & 3;                  // logical chunk at this phys slot
    int tok = slot_token[row0 + ar];
    tok = (tok < 0 || tok >= T_TOKENS) ? 0 : tok;    // pad slots hold garbage: clamp
    const unsigned short* asrc = xbf + (size_t)tok * D_IN + alc * 8;

    // B direct-load base: wave covers contiguous 1 KB per q (16 rows x 4 lquad chunks)
    const unsigned short* bptr = WTb + (size_t)expert * NKB * 8192
                                     + (wn * 32 + lrow) * 32 + lquad * 8;

    // A frag LDS offsets (shorts) within one 8 KB k-block; constant across K
    int a_off[8];
    #pragma unroll
    for (int m = 0; m < 8; m++) {
        int r = m * 16 + lrow;
        a_off[m] = r * 32 + ((lquad + (r >> 1)) & 3) * 8;
    }

    f32x4 acc[8][2];
    #pragma unroll
    for (int m = 0; m < 8; m++)
        #pragma unroll
        for (int q = 0; q < 2; q++) acc[m][q] = (f32x4){0,0,0,0};

    auto bload = [&](int kb, bf16x8 (&b)[2]) {
        const unsigned short* bp = bptr + (size_t)kb * 8192;
        #pragma unroll
        for (int q = 0; q < 2; q++) b[q] = *(const bf16x8*)(bp + q * 512);
    };
    auto stageA = [&](int st, int t2) {              // 2 async16: k-blocks 2t2, 2t2+1
        async16(&A_lds[st][0][tid * 8], asrc + (2 * t2) * 32);
        async16(&A_lds[st][1][tid * 8], asrc + (2 * t2 + 1) * 32);
    };
    auto half = [&](const unsigned short* base, bf16x8 (&b)[2]) {
        #pragma unroll
        for (int g = 0; g < 2; ++g) {                // a-frags in 2 groups of 4
            bf16x8 a[4];
            #pragma unroll
            for (int m = 0; m < 4; ++m) a[m] = *(const bf16x8*)&base[a_off[g*4+m]];
            __builtin_amdgcn_s_setprio(1);
            #pragma unroll
            for (int q = 0; q < 2; ++q)
                #pragma unroll
                for (int m = 0; m < 4; ++m)
                    acc[g*4+m][q] = __builtin_amdgcn_mfma_f32_16x16x32_bf16(
                        a[m], b[q], acc[g*4+m][q], 0, 0, 0);
            __builtin_amdgcn_s_setprio(0);
        }
    };

    // prologue: A stages oldest in vmcnt FIFO, then B(0)
    stageA(0, 0);
    stageA(1, 1);
    __builtin_amdgcn_sched_barrier(0);               // pin A stages before bload
    bf16x8 bEv[2];
    bload(0, bEv);

    for (int t = 0; t < NT2; ++t) {
        if (t == 0 || t == NT2 - 1) asm volatile("s_waitcnt vmcnt(4)" ::: "memory");
        else                        asm volatile("s_waitcnt vmcnt(6)" ::: "memory");
        asm volatile("s_barrier" ::: "memory");      // raw: no compiler vmcnt(0) drain
        bf16x8 bOdd[2];
        bload(2 * t + 1, bOdd);                      // 2 VMEM
        if (t + 2 < NT2) stageA((t + 2) % 3, t + 2); // 2 VMEM (overwrites stage t-1)
        half(&A_lds[t % 3][0][0], bEv);              // k-block 2t
        bf16x8 bEvN[2];
        if (t + 1 < NT2) bload(2 * t + 2, bEvN);     // 2 VMEM (next even block)
        half(&A_lds[t % 3][1][0], bOdd);             // k-block 2t+1
        if (t + 1 < NT2) { bEv[0] = bEvN[0]; bEv[1] = bEvN[1]; }
    }

    // epilogue: D mapping col=lane&15, row=quad*4+reg
    float bias_q[2];
    #pragma unroll
    for (int q = 0; q < 2; q++)
        bias_q[q] = eb[expert * D_OUT + wn * 32 + q * 16 + lrow];
    #pragma unroll
    for (int m = 0; m < 8; m++) {
        #pragma unroll
        for (int r = 0; r < 4; r++) {
            int slot = row0 + m * 16 + lquad * 4 + r;
            if constexpr (ROUTED) {
                float* drow = dst + (size_t)slot * D_OUT + wn * 32;
                #pragma unroll
                for (int q = 0; q < 2; q++)
                    drow[q * 16 + lrow] = acc[m][q][r] + bias_q[q];
            } else {
                int tk = slot_token[slot];
                float wgt = slot_w[slot];            // pads have wgt=0 (memset path)
                if (wgt != 0.f) {
                    #pragma unroll
                    for (int q = 0; q < 2; q++)
                        atomicAdd(dst + (size_t)tk * D_OUT + wn * 32 + q * 16 + lrow,
                                  wgt * (acc[m][q][r] + bias_q[q]));
                }
            }
        }
    }
}

// ---------------- combine: out[t] = w0*routed[s0] + w1*routed[s1] ----------------
__global__ void combine_kernel(const float* __restrict__ routed, const int* __restrict__ inv_slot,
                               const float* __restrict__ topk_w, float* __restrict__ out) {
    int flat = blockIdx.x * 256 + threadIdx.x;       // float4 index
    int t = flat >> 6, c = (flat & 63) * 4;
    int   s0 = inv_slot[t*2], s1 = inv_slot[t*2+1];
    float w0 = topk_w[t*2],   w1 = topk_w[t*2+1];
    float4 r0 = *(const float4*)(routed + (size_t)s0 * D_OUT + c);
    float4 r1 = *(const float4*)(routed + (size_t)s1 * D_OUT + c);
    float4 o;
    o.x = w0*r0.x + w1*r1.x; o.y = w0*r0.y + w1*r1.y;
    o.z = w0*r0.z + w1*r1.z; o.w = w0*r0.w + w1*r1.w;
    *(float4*)(out + (size_t)t * D_OUT + c) = o;
}

extern "C" void kernel_launch(void* const* d_in, const int* in_sizes, int n_in,
                              void* d_out, int out_size, void* d_ws, size_t ws_size,
                              hipStream_t stream) {
    const float* x  = (const float*)d_in[0];
    const float* gW = (const float*)d_in[1];
    const float* gb = (const float*)d_in[2];
    const float* eW = (const float*)d_in[3];
    const float* eb = (const float*)d_in[4];
    float* out = (float*)d_out;
    char* ws = (char*)d_ws;

    // ws layout
    float* topk_w      = (float*)(ws + 0);                 // 256 KB
    int*   topk_e      = (int*)  (ws + 262144);            // 256 KB
    int*   counts      = (int*)  (ws + 524288);            // 8 ints
    int*   cursors     = (int*)  (ws + 524320);            // 8 ints  (contiguous w/ counts)
    int*   slot_token  = (int*)  (ws + 524416);            // 266240 B (S_PAD)
    float* slot_w      = (float*)(ws + 790656);            // 266240 B (S_PAD)
    int*   inv_slot    = (int*)  (ws + 1056896);           // 262144 B (S_TOT)
    unsigned short* WTb= (unsigned short*)(ws + 7610496);  // 3 MB bf16 W k-blocked
    unsigned short* xbf= (unsigned short*)(ws + 10756224); // 48 MB bf16 x
    float* routed      = (float*)(ws + 61087872);          // 68 MB routed outputs
    const size_t NEED_ROUTED = 61087872 + (size_t)S_PAD * D_OUT * 4;  // ~129 MB
    bool use_routed = (ws_size >= NEED_ROUTED);

    convw_kernel   <<<N_EXP * NKB, 256, 0, stream>>>(eW, WTb, counts);
    gate_v5_kernel <<<T_TOKENS / 16, 256, 0, stream>>>(x, gW, gb, xbf,
                                                       topk_w, topk_e, counts);
    scatter_kernel <<<S_TOT / (256 * 4), 256, 0, stream>>>(topk_e, topk_w, counts, cursors,
                                                           slot_token, slot_w, inv_slot);
    if (use_routed) {
        moe_gemm_kernel<true><<<S_PAD / 128, 512, 0, stream>>>(xbf, WTb, eb, counts,
                                                               slot_token, slot_w, routed);
        combine_kernel<<<T_TOKENS * D_OUT / 4 / 256, 256, 0, stream>>>(routed, inv_slot,
                                                                       topk_w, out);
    } else {
        // fallback: pads must be (token=0, w=0) for the atomic path
        hipMemsetAsync(slot_token, 0, 532480, stream);
        hipMemsetAsync(out, 0, (size_t)out_size * sizeof(float), stream);
        moe_gemm_kernel<false><<<S_PAD / 128, 512, 0, stream>>>(xbf, WTb, eb, counts,
                                                                slot_token, slot_w, out);
    }
}